// Round 16
// baseline (765.630 us; speedup 1.0000x reference)
//
#include <hip/hip_runtime.h>
#include <hip/hip_bf16.h>
#include <cstdint>
#include <cstddef>

#define B_SZ    16
#define L_SZ    2048
#define DIN     64
#define DMODEL  512
#define DSTATE  16
#define NLAYERS 4
#define LN_EPS  1e-5f
#define NC      64
#define TCH     (L_SZ / NC)   // 32
#define NFUSED  (2 * DMODEL)  // 1024

typedef __bf16 bf16x8 __attribute__((ext_vector_type(8)));
typedef float  f32x4  __attribute__((ext_vector_type(4)));
typedef unsigned short u16;
typedef unsigned int   u32;

__device__ __forceinline__ u16 f2bf(float f) {
    u32 u = __builtin_bit_cast(u32, f);
    u += 0x7fffu + ((u >> 16) & 1u);
    return (u16)(u >> 16);
}
__device__ __forceinline__ float bf2f(u16 v) {
    u32 u = ((u32)v) << 16;
    return __builtin_bit_cast(float, u);
}

// a_[n] = q^(n+1), n in [0,16): ~15 muls, shallow tree
__device__ __forceinline__ void pow16(float q, float* a_) {
    float q2 = q * q, q4 = q2 * q2, q8 = q4 * q4;
    a_[0] = q;        a_[1] = q2;       a_[2] = q2 * q;   a_[3] = q4;
    a_[4] = q4 * q;   a_[5] = q4 * q2;  a_[6] = a_[5] * q; a_[7] = q8;
    a_[8] = q8 * q;   a_[9] = q8 * q2;  a_[10] = a_[9] * q; a_[11] = q8 * q4;
    a_[12] = a_[11] * q; a_[13] = a_[11] * q2; a_[14] = a_[13] * q; a_[15] = q8 * q8;
}

#define LOG2E 1.4426950408889634f

__device__ __forceinline__ void gload16(const void* g, void* l) {
    __builtin_amdgcn_global_load_lds(
        (__attribute__((address_space(1))) void*)(g),
        (__attribute__((address_space(3))) void*)(l), 16, 0, 0);
}

// ---------------------------------------------------------------------------
// Fused u|dt bf16 MFMA GEMM (round-9 proven config): 8 waves (512 thr),
// 128x128 tile, BK=64, double-buffered LDS (64 KB), counted vmcnt(4),
// two barriers per K-step. Wave tile 32x64 (2x4 frags).
// 1-D grid: bid = nb*256 + mb -> all 8 nb-blocks of one A-panel land on
// the same XCD (bid%8 == mb%8). Cols < 512 -> Cu; >= 512 -> softplus Cdt.
// ---------------------------------------------------------------------------
template <int K>
__global__ __launch_bounds__(512) void gemm_fused(
    const u16* __restrict__ A, const u16* __restrict__ BT,
    const float* __restrict__ bias, u16* __restrict__ Cu,
    u16* __restrict__ Cdt, int M)
{
    constexpr int BM = 128, BK = 64;
    constexpr int NT = K / BK;
    __shared__ u16 As[2][BM * BK];   // 2 x 16 KB
    __shared__ u16 Bs[2][BM * BK];   // 2 x 16 KB  (total 64 KB)

    const int tid = threadIdx.x;
    const int wv = tid >> 6, ln = tid & 63;
    const int mb = blockIdx.x & 255, nb = blockIdx.x >> 8;
    const int bm = mb * BM, bn = nb * BM;
    const int wm = (wv >> 1) * 32, wn = (wv & 1) * 64;   // 4x2 wave grid

    f32x4 acc[2][4];
#pragma unroll
    for (int i = 0; i < 2; ++i)
#pragma unroll
        for (int j = 0; j < 4; ++j) acc[i][j] = (f32x4){0.f, 0.f, 0.f, 0.f};

    auto stage = [&](int buf, int k0) {
#pragma unroll
        for (int i = 0; i < 2; ++i) {
            int t = i * 512 + tid;
            int m = t >> 3, s = t & 7;
            int ksrc = (s ^ (m & 7)) * 8;           // pre-swizzled source chunk
            gload16(A + (size_t)(bm + m) * K + k0 + ksrc,
                    &As[buf][(i * 512 + wv * 64) * 8]);
            gload16(BT + (size_t)(bn + m) * K + k0 + ksrc,
                    &Bs[buf][(i * 512 + wv * 64) * 8]);
        }
    };

    stage(0, 0);
    if (NT > 1) stage(1, BK);

#pragma unroll
    for (int kt = 0; kt < NT; ++kt) {
        if (kt == NT - 1) asm volatile("s_waitcnt vmcnt(0)" ::: "memory");
        else              asm volatile("s_waitcnt vmcnt(4)" ::: "memory");
        __builtin_amdgcn_s_barrier();

        const int buf = kt & 1;
#pragma unroll
        for (int ks = 0; ks < 2; ++ks) {
            bf16x8 af[2], bfr[4];
            const int g = ln >> 4, lm = ln & 15;
            const int c = ks * 4 + g;
#pragma unroll
            for (int e = 0; e < 2; ++e) {
                int ml = wm + e * 16 + lm;
                af[e] = *(const bf16x8*)&As[buf][ml * 64 + ((c ^ (ml & 7)) * 8)];
            }
#pragma unroll
            for (int f = 0; f < 4; ++f) {
                int nl = wn + f * 16 + lm;
                bfr[f] = *(const bf16x8*)&Bs[buf][nl * 64 + ((c ^ (nl & 7)) * 8)];
            }
#pragma unroll
            for (int e = 0; e < 2; ++e)
#pragma unroll
                for (int f = 0; f < 4; ++f)
                    acc[e][f] = __builtin_amdgcn_mfma_f32_16x16x32_bf16(
                        af[e], bfr[f], acc[e][f], 0, 0, 0);
        }

        asm volatile("s_waitcnt lgkmcnt(0)" ::: "memory");
        __builtin_amdgcn_s_barrier();
        if (kt + 2 < NT) stage(buf, (kt + 2) * BK);
    }

    // C/D layout: col=lane&15, row=(lane>>4)*4+reg  [verified m89/m91]
    const int cg = ln >> 4, lc = ln & 15;
    const bool uside = (bn < DMODEL);        // block-uniform
#pragma unroll
    for (int e = 0; e < 2; ++e) {
#pragma unroll
        for (int f = 0; f < 4; ++f) {
            int col = bn + wn + f * 16 + lc;
            float bv = bias[col];
#pragma unroll
            for (int r = 0; r < 4; ++r) {
                int row = bm + wm + e * 16 + cg * 4 + r;
                float v = acc[e][f][r] + bv;
                if (uside) {
                    Cu[(size_t)row * DMODEL + col] = f2bf(v);
                } else {
                    v = (v > 20.f) ? v : __logf(1.f + __expf(v));
                    Cdt[(size_t)row * DMODEL + (col - DMODEL)] = f2bf(v);
                }
            }
        }
    }
}

// ---------------------------------------------------------------------------
// Weight transpose + cast with per-layer strides (z batched).
// ---------------------------------------------------------------------------
__global__ __launch_bounds__(256) void wtrans(
    const float* __restrict__ W, u16* __restrict__ WT, int K, int N,
    size_t inStride, size_t outStride)
{
    __shared__ float tile[32][33];
    const float* Wm = W + (size_t)blockIdx.z * inStride;
    u16* WTm = WT + (size_t)blockIdx.z * outStride;
    int k0 = blockIdx.x * 32, n0 = blockIdx.y * 32;
    int tx = threadIdx.x & 31, ty = threadIdx.x >> 5;
#pragma unroll
    for (int i = 0; i < 4; ++i)
        tile[ty + 8 * i][tx] = Wm[(size_t)(k0 + ty + 8 * i) * N + n0 + tx];
    __syncthreads();
#pragma unroll
    for (int i = 0; i < 4; ++i)
        WTm[(size_t)(n0 + ty + 8 * i) * K + k0 + tx] = f2bf(tile[tx][ty + 8 * i]);
}

// ---------------------------------------------------------------------------
// W_comboT[n][k] = sum_j W_dt[j][n] * W_in[k][j]  (bf16 out, f32 accum),
// z batched with strides.
// ---------------------------------------------------------------------------
__global__ __launch_bounds__(256) void wcombo(
    const float* __restrict__ Win, const float* __restrict__ Wdt,
    u16* __restrict__ outT, int KD,
    size_t winStride, size_t wdtStride, size_t outStride)
{
    __shared__ float wi[16][516];
    __shared__ float wd[512][16];
    const float* WinL = Win + (size_t)blockIdx.z * winStride;
    const float* WdtL = Wdt + (size_t)blockIdx.z * wdtStride;
    u16* outL = outT + (size_t)blockIdx.z * outStride;
    const int k0 = blockIdx.x * 16, n0 = blockIdx.y * 16;
    const int tid = threadIdx.x;
    for (int i = tid; i < 16 * 128; i += 256) {
        int r = i >> 7, c = i & 127;
        *(float4*)&wi[r][c * 4] =
            *(const float4*)&WinL[(size_t)(k0 + r) * DMODEL + c * 4];
    }
    for (int i = tid; i < 512 * 4; i += 256) {
        int j = i >> 2, c = i & 3;
        *(float4*)&wd[j][c * 4] =
            *(const float4*)&WdtL[(size_t)j * DMODEL + n0 + c * 4];
    }
    __syncthreads();
    const int kk = tid & 15, nn = tid >> 4;
    float acc = 0.f;
#pragma unroll 8
    for (int j = 0; j < 512; ++j)
        acc = fmaf(wi[kk][j], wd[j][nn], acc);
    outL[(size_t)(n0 + nn) * KD + k0 + kk] = f2bf(acc);
}

// ---------------------------------------------------------------------------
// biascat[0:512) = b_in; biascat[512+n] = b_dt[n] + sum_j b_in[j]*W_dt[j][n]
// z batched with strides.
// ---------------------------------------------------------------------------
__global__ __launch_bounds__(256) void biasprep(
    const float* __restrict__ bin, const float* __restrict__ Wdt,
    const float* __restrict__ bdt, float* __restrict__ biascat,
    size_t binStride, size_t wdtStride, size_t bdtStride, size_t outStride)
{
    const float* binL = bin + (size_t)blockIdx.z * binStride;
    const float* WdtL = Wdt + (size_t)blockIdx.z * wdtStride;
    const float* bdtL = bdt + (size_t)blockIdx.z * bdtStride;
    float* outL = biascat + (size_t)blockIdx.z * outStride;
    int idx = blockIdx.x * 256 + threadIdx.x;
    if (idx < DMODEL) { outL[idx] = binL[idx]; return; }
    int n = idx - DMODEL;
    float acc = bdtL[n];
    for (int j = 0; j < DMODEL; ++j)
        acc = fmaf(binL[j], WdtL[(size_t)j * DMODEL + n], acc);
    outL[idx] = acc;
}

// x -> bf16 cast
__global__ __launch_bounds__(256) void castx(
    const float* __restrict__ x, u16* __restrict__ xb, int n4)
{
    int i = blockIdx.x * 256 + threadIdx.x;
    if (i < n4) {
        float4 v = ((const float4*)x)[i];
        ushort4 o;
        o.x = f2bf(v.x); o.y = f2bf(v.y); o.z = f2bf(v.z); o.w = f2bf(v.w);
        ((ushort4*)xb)[i] = o;
    }
}

// ---------------------------------------------------------------------------
// Pack W_B,W_C ([L][512][16] f32) -> WBCT [L][32][512] bf16 (transposed).
// ---------------------------------------------------------------------------
__global__ __launch_bounds__(256) void prep_wbc(
    const float* __restrict__ WB, const float* __restrict__ WC,
    u16* __restrict__ WBCT)
{
    int idx = blockIdx.x * 256 + threadIdx.x;      // over NLAYERS*32*512
    int l = idx >> 14;                             // 32*512 = 16384
    int r = idx & 16383;
    int n = r >> 9, k = r & 511;
    float v = (n < 16) ? WB[((size_t)l * DMODEL + k) * DSTATE + n]
                       : WC[((size_t)l * DMODEL + k) * DSTATE + (n - 16)];
    WBCT[((size_t)l * 32 + n) * DMODEL + k] = f2bf(v);
}

// ---------------------------------------------------------------------------
// MFMA B/C projection: Bo/Co[M,16](f32) = u[M,512](bf16) @ {W_B,W_C}.
// ---------------------------------------------------------------------------
__global__ __launch_bounds__(256) void gemm_bc_mfma(
    const u16* __restrict__ A, const u16* __restrict__ WBCT,
    float* __restrict__ Bo, float* __restrict__ Co)
{
    const int tid = threadIdx.x;
    const int wv = tid >> 6, ln = tid & 63;
    const int m0 = blockIdx.x * 64 + wv * 16;
    const int g = ln >> 4, lm = ln & 15;

    f32x4 accB = (f32x4){0.f, 0.f, 0.f, 0.f};
    f32x4 accC = (f32x4){0.f, 0.f, 0.f, 0.f};
    const u16* arow = A + (size_t)(m0 + lm) * DMODEL;
    const u16* wb = WBCT + (size_t)lm * DMODEL;
    const u16* wc = WBCT + (size_t)(lm + 16) * DMODEL;
#pragma unroll
    for (int ks = 0; ks < DMODEL / 32; ++ks) {
        int ko = ks * 32 + g * 8;
        bf16x8 a = *(const bf16x8*)&arow[ko];
        bf16x8 b = *(const bf16x8*)&wb[ko];
        bf16x8 c = *(const bf16x8*)&wc[ko];
        accB = __builtin_amdgcn_mfma_f32_16x16x32_bf16(a, b, accB, 0, 0, 0);
        accC = __builtin_amdgcn_mfma_f32_16x16x32_bf16(a, c, accC, 0, 0, 0);
    }
#pragma unroll
    for (int r = 0; r < 4; ++r) {
        int m = m0 + g * 4 + r;
        Bo[(size_t)m * DSTATE + lm] = accB[r];
        Co[(size_t)m * DSTATE + lm] = accC[r];
    }
}

// ---------------------------------------------------------------------------
// Scan pass 1 (r9 proven form: P-array always written). Geo fast path
// computes per-step decay via pow16; chunk decay P via pow16(qp).
// ---------------------------------------------------------------------------
__global__ __launch_bounds__(256) void scan_pass1(
    const u16* __restrict__ u, const u16* __restrict__ dt,
    const float* __restrict__ Bm, const float* __restrict__ A_log,
    float* __restrict__ P, float* __restrict__ S)
{
    const int tid = threadIdx.x;
    const int d = blockIdx.x * 256 + tid;
    const int c = blockIdx.y, b = blockIdx.z;
    __shared__ float Bs[TCH][DSTATE];

    const float* Bsrc = Bm + ((size_t)b * L_SZ + (size_t)c * TCH) * DSTATE;
    for (int i = tid; i < TCH * DSTATE / 4; i += 256)
        ((float4*)Bs)[i] = ((const float4*)Bsrc)[i];

    float Ac[16];
#pragma unroll
    for (int n = 0; n < 16; ++n) Ac[n] = -__expf(A_log[d * DSTATE + n]);
    bool geo = true;
#pragma unroll
    for (int n = 1; n < 16; ++n)
        geo &= fabsf(Ac[n] - (n + 1) * Ac[0]) <= 1e-4f * (n + 1) * fabsf(Ac[0]);
    __syncthreads();

    float s[16];
#pragma unroll
    for (int n = 0; n < 16; ++n) s[n] = 0.f;

    const size_t base = ((size_t)b * L_SZ + (size_t)c * TCH) * DMODEL + d;
    size_t o = (((size_t)b * NC + c) * DMODEL + d) * DSTATE;

    if (geo) {
        const float cK = Ac[0] * LOG2E;
        float qp = 1.f;
#pragma unroll 2
        for (int t = 0; t < TCH; ++t) {
            float dtv = bf2f(dt[base + (size_t)t * DMODEL]);
            float uv  = bf2f(u [base + (size_t)t * DMODEL]);
            float du = dtv * uv;
            float q = exp2f(dtv * cK);
            qp *= q;
            float a_[16];
            pow16(q, a_);
#pragma unroll
            for (int n = 0; n < 16; ++n)
                s[n] = fmaf(a_[n], s[n], du * Bs[t][n]);
        }
        float p_[16];
        pow16(qp, p_);
#pragma unroll
        for (int n = 0; n < 16; ++n) { P[o + n] = p_[n]; S[o + n] = s[n]; }
    } else {
        float p[16];
#pragma unroll
        for (int n = 0; n < 16; ++n) p[n] = 1.f;
#pragma unroll 2
        for (int t = 0; t < TCH; ++t) {
            float dtv = bf2f(dt[base + (size_t)t * DMODEL]);
            float uv  = bf2f(u [base + (size_t)t * DMODEL]);
            float du = dtv * uv;
#pragma unroll
            for (int n = 0; n < 16; ++n) {
                float a = __expf(dtv * Ac[n]);
                p[n] *= a;
                s[n] = fmaf(a, s[n], du * Bs[t][n]);
            }
        }
#pragma unroll
        for (int n = 0; n < 16; ++n) { P[o + n] = p[n]; S[o + n] = s[n]; }
    }
}

// ---------------------------------------------------------------------------
// Chunk fix-up: sequential over NC chunks per (b,d,n).
// H0 MAY ALIAS P: P[o] is read before H0[o] is written (one thread per o).
// ---------------------------------------------------------------------------
__global__ __launch_bounds__(256) void scan_fix(
    const float* __restrict__ P, const float* __restrict__ S,
    float* __restrict__ H0)
{
    const int idx = blockIdx.x * 256 + threadIdx.x;   // over B*D*N
    const int dn = idx & (DMODEL * DSTATE - 1);
    const int b = idx >> 13;                          // D*N = 8192
    float h = 0.f;
#pragma unroll
    for (int c = 0; c < NC; ++c) {
        size_t o = (((size_t)b * NC + c) << 13) + dn;
        float p = P[o];
        float sv = S[o];
        H0[o] = h;
        h = fmaf(p, h, sv);
    }
}

// ---------------------------------------------------------------------------
// Scan pass 2 (r9 proven form): seeded with H0; emits y bf16
// (+ fp32 last-token row).
// ---------------------------------------------------------------------------
__global__ __launch_bounds__(256) void scan_pass2(
    const u16* __restrict__ u, const u16* __restrict__ dt,
    const float* __restrict__ Bm, const float* __restrict__ Cm,
    const float* __restrict__ A_log, const float* __restrict__ Dskip,
    const float* __restrict__ H0, u16* __restrict__ yb,
    float* __restrict__ ylast)
{
    const int tid = threadIdx.x;
    const int d = blockIdx.x * 256 + tid;
    const int c = blockIdx.y, b = blockIdx.z;
    __shared__ float Bs[TCH][DSTATE];
    __shared__ float Cs[TCH][DSTATE];

    const float* Bsrc = Bm + ((size_t)b * L_SZ + (size_t)c * TCH) * DSTATE;
    const float* Csrc = Cm + ((size_t)b * L_SZ + (size_t)c * TCH) * DSTATE;
    for (int i = tid; i < TCH * DSTATE / 4; i += 256) {
        ((float4*)Bs)[i] = ((const float4*)Bsrc)[i];
        ((float4*)Cs)[i] = ((const float4*)Csrc)[i];
    }

    float Ac[16];
#pragma unroll
    for (int n = 0; n < 16; ++n) Ac[n] = -__expf(A_log[d * DSTATE + n]);
    bool geo = true;
#pragma unroll
    for (int n = 1; n < 16; ++n)
        geo &= fabsf(Ac[n] - (n + 1) * Ac[0]) <= 1e-4f * (n + 1) * fabsf(Ac[0]);
    const float Dk = Dskip[d];

    float h[16];
    size_t ho = (((size_t)b * NC + c) * DMODEL + d) * DSTATE;
#pragma unroll
    for (int n = 0; n < 16; ++n) h[n] = H0[ho + n];
    __syncthreads();

    const size_t base = ((size_t)b * L_SZ + (size_t)c * TCH) * DMODEL + d;

    if (geo) {
        const float cK = Ac[0] * LOG2E;
#pragma unroll 2
        for (int t = 0; t < TCH; ++t) {
            float dtv = bf2f(dt[base + (size_t)t * DMODEL]);
            float uv  = bf2f(u [base + (size_t)t * DMODEL]);
            float du = dtv * uv;
            float q = exp2f(dtv * cK);
            float a_[16];
            pow16(q, a_);
            float yv = 0.f;
#pragma unroll
            for (int n = 0; n < 16; ++n) {
                h[n] = fmaf(a_[n], h[n], du * Bs[t][n]);
                yv = fmaf(h[n], Cs[t][n], yv);
            }
            yv = fmaf(uv, Dk, yv);
            yb[base + (size_t)t * DMODEL] = f2bf(yv);
            if (c == NC - 1 && t == TCH - 1) ylast[(size_t)b * DMODEL + d] = yv;
        }
    } else {
#pragma unroll 2
        for (int t = 0; t < TCH; ++t) {
            float dtv = bf2f(dt[base + (size_t)t * DMODEL]);
            float uv  = bf2f(u [base + (size_t)t * DMODEL]);
            float du = dtv * uv;
            float yv = 0.f;
#pragma unroll
            for (int n = 0; n < 16; ++n) {
                float a = __expf(dtv * Ac[n]);
                h[n] = fmaf(a, h[n], du * Bs[t][n]);
                yv = fmaf(h[n], Cs[t][n], yv);
            }
            yv = fmaf(uv, Dk, yv);
            yb[base + (size_t)t * DMODEL] = f2bf(yv);
            if (c == NC - 1 && t == TCH - 1) ylast[(size_t)b * DMODEL + d] = yv;
        }
    }
}

// ---------------------------------------------------------------------------
// LayerNorm(last token) + head. One block per batch.
// ---------------------------------------------------------------------------
__global__ __launch_bounds__(256) void ln_head_kernel(
    const float* __restrict__ ylast, const float* __restrict__ g,
    const float* __restrict__ bb, const float* __restrict__ hw,
    const float* __restrict__ hb, float* __restrict__ out)
{
    const int b = blockIdx.x;
    const int tid = threadIdx.x;
    const float* row = ylast + (size_t)b * DMODEL;
    float v0 = row[tid], v1 = row[tid + 256];
    float s = v0 + v1;
    float s2 = v0 * v0 + v1 * v1;
#pragma unroll
    for (int o = 32; o >= 1; o >>= 1) {
        s += __shfl_xor(s, o);
        s2 += __shfl_xor(s2, o);
    }
    __shared__ float red[8];
    const int w = tid >> 6;
    if ((tid & 63) == 0) { red[w] = s; red[4 + w] = s2; }
    __syncthreads();
    s = red[0] + red[1] + red[2] + red[3];
    s2 = red[4] + red[5] + red[6] + red[7];
    float mu = s * (1.f / DMODEL);
    float var = s2 * (1.f / DMODEL) - mu * mu;
    float r = rsqrtf(var + LN_EPS);
    float c = ((v0 - mu) * r * g[tid] + bb[tid]) * hw[tid]
            + ((v1 - mu) * r * g[tid + 256] + bb[tid + 256]) * hw[tid + 256];
#pragma unroll
    for (int o = 32; o >= 1; o >>= 1) c += __shfl_xor(c, o);
    __syncthreads();
    if ((tid & 63) == 0) red[w] = c;
    __syncthreads();
    if (tid == 0) out[b] = red[0] + red[1] + red[2] + red[3] + hb[0];
}

// ---------------------------------------------------------------------------
extern "C" void kernel_launch(void* const* d_in, const int* in_sizes, int n_in,
                              void* d_out, int out_size, void* d_ws, size_t ws_size,
                              hipStream_t stream)
{
    const float* x      = (const float*)d_in[0];
    const float* W_in0  = (const float*)d_in[1];
    const float* b_in0  = (const float*)d_in[2];
    const float* W_in   = (const float*)d_in[3];
    const float* b_in   = (const float*)d_in[4];
    const float* A_log  = (const float*)d_in[5];
    const float* D_skip = (const float*)d_in[6];
    const float* W_dt   = (const float*)d_in[7];
    const float* b_dt   = (const float*)d_in[8];
    const float* W_B    = (const float*)d_in[9];
    const float* W_C    = (const float*)d_in[10];
    const float* ln_g   = (const float*)d_in[11];
    const float* ln_b   = (const float*)d_in[12];
    const float* head_w = (const float*)d_in[13];
    const float* head_b = (const float*)d_in[14];
    float* out = (float*)d_out;

    const size_t BLD = (size_t)B_SZ * L_SZ * DMODEL;         // 16.78M
    const size_t BLN = (size_t)B_SZ * L_SZ * DSTATE;         // 0.52M
    const size_t BCD = (size_t)B_SZ * NC * DMODEL * DSTATE;  // 8.39M (NC=64)
    const size_t XBN = (size_t)B_SZ * L_SZ * DIN;            // 2.10M

    // fp32 ~71 MB + bf16 ~108 MB = ~180 MB (H0 aliases P)
    float* fp = (float*)d_ws;
    float* Bbuf  = fp; fp += BLN;
    float* Cbuf  = fp; fp += BLN;
    float* Pbuf  = fp; fp += BCD;     // doubles as H0 after scan_fix
    float* Sbuf  = fp; fp += BCD;
    float* ylast = fp; fp += (size_t)B_SZ * DMODEL;
    float* biascat = fp; fp += (size_t)NLAYERS * NFUSED;
    u16* hp = (u16*)fp;
    u16* xb    = hp; hp += XBN;
    u16* ub    = hp; hp += BLD;
    u16* dtb   = hp; hp += BLD;
    u16* ybuf  = hp; hp += BLD;
    u16* BT0   = hp; hp += (size_t)NFUSED * DIN;                    // layer 0
    u16* BTcat = hp; hp += (size_t)(NLAYERS - 1) * NFUSED * DMODEL; // layers 1-3
    u16* WBCT  = hp; hp += (size_t)NLAYERS * 32 * DMODEL;

    const int M = B_SZ * L_SZ;   // 32768

    // ---- prep ----
    castx<<<(XBN / 4 + 255) / 256, 256, 0, stream>>>(x, xb, XBN / 4);
    prep_wbc<<<(NLAYERS * 32 * DMODEL) / 256, 256, 0, stream>>>(W_B, W_C, WBCT);
    // layer 0: BT0 = [W_in0^T | (W_in0@W_dt0)^T]  (1024 rows, K=64)
    wtrans<<<dim3(DIN / 32, DMODEL / 32, 1), 256, 0, stream>>>(
        W_in0, BT0, DIN, DMODEL, 0, 0);
    wcombo<<<dim3(DIN / 16, DMODEL / 16, 1), 256, 0, stream>>>(
        W_in0, W_dt, BT0 + (size_t)DMODEL * DIN, DIN, 0, 0, 0);
    biasprep<<<dim3(4, 1, 1), 256, 0, stream>>>(
        b_in0, W_dt, b_dt, biascat, 0, 0, 0, 0);
    // layers 1-3 batched over z
    wtrans<<<dim3(DMODEL / 32, DMODEL / 32, NLAYERS - 1), 256, 0, stream>>>(
        W_in, BTcat, DMODEL, DMODEL,
        (size_t)DMODEL * DMODEL, (size_t)NFUSED * DMODEL);
    wcombo<<<dim3(DMODEL / 16, DMODEL / 16, NLAYERS - 1), 256, 0, stream>>>(
        W_in, W_dt + (size_t)DMODEL * DMODEL,
        BTcat + (size_t)DMODEL * DMODEL, DMODEL,
        (size_t)DMODEL * DMODEL, (size_t)DMODEL * DMODEL,
        (size_t)NFUSED * DMODEL);
    biasprep<<<dim3(4, 1, NLAYERS - 1), 256, 0, stream>>>(
        b_in, W_dt + (size_t)DMODEL * DMODEL, b_dt + DMODEL, biascat + NFUSED,
        DMODEL, (size_t)DMODEL * DMODEL, DMODEL, NFUSED);

    // ---- layers ----
    for (int l = 0; l < NLAYERS; ++l) {
        if (l == 0) {
            gemm_fused<DIN><<<(M / 128) * (NFUSED / 128), 512, 0, stream>>>(
                xb, BT0, biascat, ub, dtb, M);
        } else {
            gemm_fused<DMODEL><<<(M / 128) * (NFUSED / 128), 512, 0, stream>>>(
                ybuf, BTcat + (size_t)(l - 1) * NFUSED * DMODEL,
                biascat + (size_t)l * NFUSED, ub, dtb, M);
        }
        gemm_bc_mfma<<<M / 64, 256, 0, stream>>>(
            ub, WBCT + (size_t)l * 32 * DMODEL, Bbuf, Cbuf);
        const float* Al = A_log + (size_t)l * DMODEL * DSTATE;
        scan_pass1<<<dim3(DMODEL / 256, NC, B_SZ), 256, 0, stream>>>(
            ub, dtb, Bbuf, Al, Pbuf, Sbuf);
        scan_fix<<<(B_SZ * DMODEL * DSTATE) / 256, 256, 0, stream>>>(
            Pbuf, Sbuf, Pbuf /* H0 aliases P */);
        scan_pass2<<<dim3(DMODEL / 256, NC, B_SZ), 256, 0, stream>>>(
            ub, dtb, Bbuf, Cbuf, Al, D_skip + (size_t)l * DMODEL,
            Pbuf /* H0 */, ybuf, ylast);
    }

    ln_head_kernel<<<B_SZ, 256, 0, stream>>>(ylast, ln_g, ln_b, head_w, head_b, out);
}

// Round 17
// 690.262 us; speedup vs baseline: 1.1092x; 1.1092x over previous
//
#include <hip/hip_runtime.h>
#include <hip/hip_bf16.h>
#include <cstdint>
#include <cstddef>

#define B_SZ    16
#define L_SZ    2048
#define DIN     64
#define DMODEL  512
#define DSTATE  16
#define NLAYERS 4
#define LN_EPS  1e-5f
#define NC      32
#define TCH     (L_SZ / NC)   // 64
#define NFUSED  (2 * DMODEL)  // 1024

typedef __bf16 bf16x8 __attribute__((ext_vector_type(8)));
typedef float  f32x4  __attribute__((ext_vector_type(4)));
typedef unsigned short u16;
typedef unsigned int   u32;

__device__ __forceinline__ u16 f2bf(float f) {
    u32 u = __builtin_bit_cast(u32, f);
    u += 0x7fffu + ((u >> 16) & 1u);
    return (u16)(u >> 16);
}
__device__ __forceinline__ float bf2f(u16 v) {
    u32 u = ((u32)v) << 16;
    return __builtin_bit_cast(float, u);
}

// a_[n] = q^(n+1), n in [0,16): ~15 muls, shallow tree
__device__ __forceinline__ void pow16(float q, float* a_) {
    float q2 = q * q, q4 = q2 * q2, q8 = q4 * q4;
    a_[0] = q;        a_[1] = q2;       a_[2] = q2 * q;   a_[3] = q4;
    a_[4] = q4 * q;   a_[5] = q4 * q2;  a_[6] = a_[5] * q; a_[7] = q8;
    a_[8] = q8 * q;   a_[9] = q8 * q2;  a_[10] = a_[9] * q; a_[11] = q8 * q4;
    a_[12] = a_[11] * q; a_[13] = a_[11] * q2; a_[14] = a_[13] * q; a_[15] = q8 * q8;
}

#define LOG2E 1.4426950408889634f

__device__ __forceinline__ void gload16(const void* g, void* l) {
    __builtin_amdgcn_global_load_lds(
        (__attribute__((address_space(1))) void*)(g),
        (__attribute__((address_space(3))) void*)(l), 16, 0, 0);
}

// ---------------------------------------------------------------------------
// Fused u|dt bf16 MFMA GEMM, 8 waves (512 thr), 128x128 tile, BK=32.
// LDS = 2buf x (A+B) x 8KB = 32 KB -> 4 blocks/CU x 8 waves = 8 waves/SIMD.
// Counted-vmcnt double buffer: each thread stages exactly 2 chunks per
// K-tile (1 A + 1 B); wait vmcnt(2) keeps next tile's loads in flight.
// Swizzle: stage ksrc = (s ^ ((m>>1)&3))*8, read slot g ^ ((ml>>1)&3)
// -> 8 banks x 2 lanes on ds_read_b128 (2-way = free).
// 1-D grid bid = nb*256 + mb -> bid%8 == mb%8: the 8 nb-blocks sharing an
// A-panel land on one XCD. Cols < 512 -> Cu; cols >= 512 -> softplus -> Cdt.
// ---------------------------------------------------------------------------
template <int K>
__global__ __launch_bounds__(512) void gemm_fused(
    const u16* __restrict__ A, const u16* __restrict__ BT,
    const float* __restrict__ bias, u16* __restrict__ Cu,
    u16* __restrict__ Cdt, int M)
{
    constexpr int BM = 128, BK = 32;
    constexpr int NT = K / BK;
    __shared__ u16 As[2][BM * BK];   // 2 x 8 KB
    __shared__ u16 Bs[2][BM * BK];   // 2 x 8 KB  (total 32 KB)

    const int tid = threadIdx.x;
    const int wv = tid >> 6, ln = tid & 63;
    const int mb = blockIdx.x & 255, nb = blockIdx.x >> 8;
    const int bm = mb * BM, bn = nb * BM;
    const int wm = (wv >> 1) * 32, wn = (wv & 1) * 64;   // 4x2 wave grid

    f32x4 acc[2][4];
#pragma unroll
    for (int i = 0; i < 2; ++i)
#pragma unroll
        for (int j = 0; j < 4; ++j) acc[i][j] = (f32x4){0.f, 0.f, 0.f, 0.f};

    // one 128x32 A-tile + B-tile: 512 chunks each -> 1 A + 1 B load/thread
    const int sm = tid >> 2, ss = tid & 3;
    const int ksrc = (ss ^ ((sm >> 1) & 3)) * 8;        // pre-swizzled source
    auto stage = [&](int buf, int k0) {
        gload16(A + (size_t)(bm + sm) * K + k0 + ksrc, &As[buf][(wv * 64) * 8]);
        gload16(BT + (size_t)(bn + sm) * K + k0 + ksrc, &Bs[buf][(wv * 64) * 8]);
    };

    stage(0, 0);
    if (NT > 1) stage(1, BK);

#pragma unroll
    for (int kt = 0; kt < NT; ++kt) {
        if (kt == NT - 1) asm volatile("s_waitcnt vmcnt(0)" ::: "memory");
        else              asm volatile("s_waitcnt vmcnt(2)" ::: "memory");
        __builtin_amdgcn_s_barrier();

        const int buf = kt & 1;
        const int g = ln >> 4, lm = ln & 15;
        bf16x8 af[2], bfr[4];
#pragma unroll
        for (int e = 0; e < 2; ++e) {
            int ml = wm + e * 16 + lm;
            af[e] = *(const bf16x8*)&As[buf][ml * 32 + ((g ^ ((ml >> 1) & 3)) * 8)];
        }
#pragma unroll
        for (int f = 0; f < 4; ++f) {
            int nl = wn + f * 16 + lm;
            bfr[f] = *(const bf16x8*)&Bs[buf][nl * 32 + ((g ^ ((nl >> 1) & 3)) * 8)];
        }
#pragma unroll
        for (int e = 0; e < 2; ++e)
#pragma unroll
            for (int f = 0; f < 4; ++f)
                acc[e][f] = __builtin_amdgcn_mfma_f32_16x16x32_bf16(
                    af[e], bfr[f], acc[e][f], 0, 0, 0);

        asm volatile("s_waitcnt lgkmcnt(0)" ::: "memory");
        __builtin_amdgcn_s_barrier();
        if (kt + 2 < NT) stage(buf, (kt + 2) * BK);
    }

    // C/D layout: col=lane&15, row=(lane>>4)*4+reg  [verified m89/m91]
    const int cg = ln >> 4, lc = ln & 15;
    const bool uside = (bn < DMODEL);        // block-uniform
#pragma unroll
    for (int e = 0; e < 2; ++e) {
#pragma unroll
        for (int f = 0; f < 4; ++f) {
            int col = bn + wn + f * 16 + lc;
            float bv = bias[col];
#pragma unroll
            for (int r = 0; r < 4; ++r) {
                int row = bm + wm + e * 16 + cg * 4 + r;
                float v = acc[e][f][r] + bv;
                if (uside) {
                    Cu[(size_t)row * DMODEL + col] = f2bf(v);
                } else {
                    v = (v > 20.f) ? v : __logf(1.f + __expf(v));
                    Cdt[(size_t)row * DMODEL + (col - DMODEL)] = f2bf(v);
                }
            }
        }
    }
}

// ---------------------------------------------------------------------------
// Weight transpose + cast with per-layer strides (z batched).
// ---------------------------------------------------------------------------
__global__ __launch_bounds__(256) void wtrans(
    const float* __restrict__ W, u16* __restrict__ WT, int K, int N,
    size_t inStride, size_t outStride)
{
    __shared__ float tile[32][33];
    const float* Wm = W + (size_t)blockIdx.z * inStride;
    u16* WTm = WT + (size_t)blockIdx.z * outStride;
    int k0 = blockIdx.x * 32, n0 = blockIdx.y * 32;
    int tx = threadIdx.x & 31, ty = threadIdx.x >> 5;
#pragma unroll
    for (int i = 0; i < 4; ++i)
        tile[ty + 8 * i][tx] = Wm[(size_t)(k0 + ty + 8 * i) * N + n0 + tx];
    __syncthreads();
#pragma unroll
    for (int i = 0; i < 4; ++i)
        WTm[(size_t)(n0 + ty + 8 * i) * K + k0 + tx] = f2bf(tile[tx][ty + 8 * i]);
}

// ---------------------------------------------------------------------------
// W_comboT[n][k] = sum_j W_dt[j][n] * W_in[k][j]  (bf16 out, f32 accum),
// z batched with strides.
// ---------------------------------------------------------------------------
__global__ __launch_bounds__(256) void wcombo(
    const float* __restrict__ Win, const float* __restrict__ Wdt,
    u16* __restrict__ outT, int KD,
    size_t winStride, size_t wdtStride, size_t outStride)
{
    __shared__ float wi[16][516];
    __shared__ float wd[512][16];
    const float* WinL = Win + (size_t)blockIdx.z * winStride;
    const float* WdtL = Wdt + (size_t)blockIdx.z * wdtStride;
    u16* outL = outT + (size_t)blockIdx.z * outStride;
    const int k0 = blockIdx.x * 16, n0 = blockIdx.y * 16;
    const int tid = threadIdx.x;
    for (int i = tid; i < 16 * 128; i += 256) {
        int r = i >> 7, c = i & 127;
        *(float4*)&wi[r][c * 4] =
            *(const float4*)&WinL[(size_t)(k0 + r) * DMODEL + c * 4];
    }
    for (int i = tid; i < 512 * 4; i += 256) {
        int j = i >> 2, c = i & 3;
        *(float4*)&wd[j][c * 4] =
            *(const float4*)&WdtL[(size_t)j * DMODEL + n0 + c * 4];
    }
    __syncthreads();
    const int kk = tid & 15, nn = tid >> 4;
    float acc = 0.f;
#pragma unroll 8
    for (int j = 0; j < 512; ++j)
        acc = fmaf(wi[kk][j], wd[j][nn], acc);
    outL[(size_t)(n0 + nn) * KD + k0 + kk] = f2bf(acc);
}

// ---------------------------------------------------------------------------
// biascat[0:512) = b_in; biascat[512+n] = b_dt[n] + sum_j b_in[j]*W_dt[j][n]
// z batched with strides.
// ---------------------------------------------------------------------------
__global__ __launch_bounds__(256) void biasprep(
    const float* __restrict__ bin, const float* __restrict__ Wdt,
    const float* __restrict__ bdt, float* __restrict__ biascat,
    size_t binStride, size_t wdtStride, size_t bdtStride, size_t outStride)
{
    const float* binL = bin + (size_t)blockIdx.z * binStride;
    const float* WdtL = Wdt + (size_t)blockIdx.z * wdtStride;
    const float* bdtL = bdt + (size_t)blockIdx.z * bdtStride;
    float* outL = biascat + (size_t)blockIdx.z * outStride;
    int idx = blockIdx.x * 256 + threadIdx.x;
    if (idx < DMODEL) { outL[idx] = binL[idx]; return; }
    int n = idx - DMODEL;
    float acc = bdtL[n];
    for (int j = 0; j < DMODEL; ++j)
        acc = fmaf(binL[j], WdtL[(size_t)j * DMODEL + n], acc);
    outL[idx] = acc;
}

// x -> bf16 cast
__global__ __launch_bounds__(256) void castx(
    const float* __restrict__ x, u16* __restrict__ xb, int n4)
{
    int i = blockIdx.x * 256 + threadIdx.x;
    if (i < n4) {
        float4 v = ((const float4*)x)[i];
        ushort4 o;
        o.x = f2bf(v.x); o.y = f2bf(v.y); o.z = f2bf(v.z); o.w = f2bf(v.w);
        ((ushort4*)xb)[i] = o;
    }
}

// ---------------------------------------------------------------------------
// Pack W_B,W_C ([L][512][16] f32) -> WBCT [L][32][512] bf16 (transposed).
// ---------------------------------------------------------------------------
__global__ __launch_bounds__(256) void prep_wbc(
    const float* __restrict__ WB, const float* __restrict__ WC,
    u16* __restrict__ WBCT)
{
    int idx = blockIdx.x * 256 + threadIdx.x;      // over NLAYERS*32*512
    int l = idx >> 14;                             // 32*512 = 16384
    int r = idx & 16383;
    int n = r >> 9, k = r & 511;
    float v = (n < 16) ? WB[((size_t)l * DMODEL + k) * DSTATE + n]
                       : WC[((size_t)l * DMODEL + k) * DSTATE + (n - 16)];
    WBCT[((size_t)l * 32 + n) * DMODEL + k] = f2bf(v);
}

// ---------------------------------------------------------------------------
// MFMA B/C projection: Bo/Co[M,16](f32) = u[M,512](bf16) @ {W_B,W_C}.
// ---------------------------------------------------------------------------
__global__ __launch_bounds__(256) void gemm_bc_mfma(
    const u16* __restrict__ A, const u16* __restrict__ WBCT,
    float* __restrict__ Bo, float* __restrict__ Co)
{
    const int tid = threadIdx.x;
    const int wv = tid >> 6, ln = tid & 63;
    const int m0 = blockIdx.x * 64 + wv * 16;
    const int g = ln >> 4, lm = ln & 15;

    f32x4 accB = (f32x4){0.f, 0.f, 0.f, 0.f};
    f32x4 accC = (f32x4){0.f, 0.f, 0.f, 0.f};
    const u16* arow = A + (size_t)(m0 + lm) * DMODEL;
    const u16* wb = WBCT + (size_t)lm * DMODEL;
    const u16* wc = WBCT + (size_t)(lm + 16) * DMODEL;
#pragma unroll
    for (int ks = 0; ks < DMODEL / 32; ++ks) {
        int ko = ks * 32 + g * 8;
        bf16x8 a = *(const bf16x8*)&arow[ko];
        bf16x8 b = *(const bf16x8*)&wb[ko];
        bf16x8 c = *(const bf16x8*)&wc[ko];
        accB = __builtin_amdgcn_mfma_f32_16x16x32_bf16(a, b, accB, 0, 0, 0);
        accC = __builtin_amdgcn_mfma_f32_16x16x32_bf16(a, c, accC, 0, 0, 0);
    }
#pragma unroll
    for (int r = 0; r < 4; ++r) {
        int m = m0 + g * 4 + r;
        Bo[(size_t)m * DSTATE + lm] = accB[r];
        Co[(size_t)m * DSTATE + lm] = accC[r];
    }
}

// ---------------------------------------------------------------------------
// Scan pass 1: thread = one d, h[n] in regs. B-chunk staged in LDS.
// Geo fast path: a[n] = q^(n+1); chunk decay P via pow16(qp).
// ---------------------------------------------------------------------------
__global__ __launch_bounds__(256) void scan_pass1(
    const u16* __restrict__ u, const u16* __restrict__ dt,
    const float* __restrict__ Bm, const float* __restrict__ A_log,
    float* __restrict__ P, float* __restrict__ S)
{
    const int tid = threadIdx.x;
    const int d = blockIdx.x * 256 + tid;
    const int c = blockIdx.y, b = blockIdx.z;
    __shared__ float Bs[TCH][DSTATE];

    const float* Bsrc = Bm + ((size_t)b * L_SZ + (size_t)c * TCH) * DSTATE;
    for (int i = tid; i < TCH * DSTATE / 4; i += 256)
        ((float4*)Bs)[i] = ((const float4*)Bsrc)[i];

    float Ac[16];
#pragma unroll
    for (int n = 0; n < 16; ++n) Ac[n] = -__expf(A_log[d * DSTATE + n]);
    bool geo = true;
#pragma unroll
    for (int n = 1; n < 16; ++n)
        geo &= fabsf(Ac[n] - (n + 1) * Ac[0]) <= 1e-4f * (n + 1) * fabsf(Ac[0]);
    __syncthreads();

    float s[16];
#pragma unroll
    for (int n = 0; n < 16; ++n) s[n] = 0.f;

    const size_t base = ((size_t)b * L_SZ + (size_t)c * TCH) * DMODEL + d;
    size_t o = (((size_t)b * NC + c) * DMODEL + d) * DSTATE;

    if (geo) {
        const float cK = Ac[0] * LOG2E;
        float qp = 1.f;
#pragma unroll 2
        for (int t = 0; t < TCH; ++t) {
            float dtv = bf2f(dt[base + (size_t)t * DMODEL]);
            float uv  = bf2f(u [base + (size_t)t * DMODEL]);
            float du = dtv * uv;
            float q = exp2f(dtv * cK);
            qp *= q;
            float a_[16];
            pow16(q, a_);
#pragma unroll
            for (int n = 0; n < 16; ++n)
                s[n] = fmaf(a_[n], s[n], du * Bs[t][n]);
        }
        float p_[16];
        pow16(qp, p_);
#pragma unroll
        for (int n = 0; n < 16; ++n) { P[o + n] = p_[n]; S[o + n] = s[n]; }
    } else {
        float p[16];
#pragma unroll
        for (int n = 0; n < 16; ++n) p[n] = 1.f;
#pragma unroll 2
        for (int t = 0; t < TCH; ++t) {
            float dtv = bf2f(dt[base + (size_t)t * DMODEL]);
            float uv  = bf2f(u [base + (size_t)t * DMODEL]);
            float du = dtv * uv;
#pragma unroll
            for (int n = 0; n < 16; ++n) {
                float a = __expf(dtv * Ac[n]);
                p[n] *= a;
                s[n] = fmaf(a, s[n], du * Bs[t][n]);
            }
        }
#pragma unroll
        for (int n = 0; n < 16; ++n) { P[o + n] = p[n]; S[o + n] = s[n]; }
    }
}

// ---------------------------------------------------------------------------
// Chunk fix-up: sequential over NC chunks per (b,d,n).
// ---------------------------------------------------------------------------
__global__ __launch_bounds__(256) void scan_fix(
    const float* __restrict__ P, const float* __restrict__ S,
    float* __restrict__ H0)
{
    const int idx = blockIdx.x * 256 + threadIdx.x;   // over B*D*N
    const int dn = idx & (DMODEL * DSTATE - 1);
    const int b = idx >> 13;                          // D*N = 8192
    float h = 0.f;
#pragma unroll
    for (int c = 0; c < NC; ++c) {
        size_t o = (((size_t)b * NC + c) << 13) + dn;
        H0[o] = h;
        h = fmaf(P[o], h, S[o]);
    }
}

// ---------------------------------------------------------------------------
// Scan pass 2: seeded with H0; emit y bf16 (+ fp32 last-token row).
// ---------------------------------------------------------------------------
__global__ __launch_bounds__(256) void scan_pass2(
    const u16* __restrict__ u, const u16* __restrict__ dt,
    const float* __restrict__ Bm, const float* __restrict__ Cm,
    const float* __restrict__ A_log, const float* __restrict__ Dskip,
    const float* __restrict__ H0, u16* __restrict__ yb,
    float* __restrict__ ylast)
{
    const int tid = threadIdx.x;
    const int d = blockIdx.x * 256 + tid;
    const int c = blockIdx.y, b = blockIdx.z;
    __shared__ float Bs[TCH][DSTATE];
    __shared__ float Cs[TCH][DSTATE];

    const float* Bsrc = Bm + ((size_t)b * L_SZ + (size_t)c * TCH) * DSTATE;
    const float* Csrc = Cm + ((size_t)b * L_SZ + (size_t)c * TCH) * DSTATE;
    for (int i = tid; i < TCH * DSTATE / 4; i += 256) {
        ((float4*)Bs)[i] = ((const float4*)Bsrc)[i];
        ((float4*)Cs)[i] = ((const float4*)Csrc)[i];
    }

    float Ac[16];
#pragma unroll
    for (int n = 0; n < 16; ++n) Ac[n] = -__expf(A_log[d * DSTATE + n]);
    bool geo = true;
#pragma unroll
    for (int n = 1; n < 16; ++n)
        geo &= fabsf(Ac[n] - (n + 1) * Ac[0]) <= 1e-4f * (n + 1) * fabsf(Ac[0]);
    const float Dk = Dskip[d];

    float h[16];
    size_t ho = (((size_t)b * NC + c) * DMODEL + d) * DSTATE;
#pragma unroll
    for (int n = 0; n < 16; ++n) h[n] = H0[ho + n];
    __syncthreads();

    const size_t base = ((size_t)b * L_SZ + (size_t)c * TCH) * DMODEL + d;

    if (geo) {
        const float cK = Ac[0] * LOG2E;
#pragma unroll 2
        for (int t = 0; t < TCH; ++t) {
            float dtv = bf2f(dt[base + (size_t)t * DMODEL]);
            float uv  = bf2f(u [base + (size_t)t * DMODEL]);
            float du = dtv * uv;
            float q = exp2f(dtv * cK);
            float a_[16];
            pow16(q, a_);
            float yv = 0.f;
#pragma unroll
            for (int n = 0; n < 16; ++n) {
                h[n] = fmaf(a_[n], h[n], du * Bs[t][n]);
                yv = fmaf(h[n], Cs[t][n], yv);
            }
            yv = fmaf(uv, Dk, yv);
            yb[base + (size_t)t * DMODEL] = f2bf(yv);
            if (c == NC - 1 && t == TCH - 1) ylast[(size_t)b * DMODEL + d] = yv;
        }
    } else {
#pragma unroll 2
        for (int t = 0; t < TCH; ++t) {
            float dtv = bf2f(dt[base + (size_t)t * DMODEL]);
            float uv  = bf2f(u [base + (size_t)t * DMODEL]);
            float du = dtv * uv;
            float yv = 0.f;
#pragma unroll
            for (int n = 0; n < 16; ++n) {
                float a = __expf(dtv * Ac[n]);
                h[n] = fmaf(a, h[n], du * Bs[t][n]);
                yv = fmaf(h[n], Cs[t][n], yv);
            }
            yv = fmaf(uv, Dk, yv);
            yb[base + (size_t)t * DMODEL] = f2bf(yv);
            if (c == NC - 1 && t == TCH - 1) ylast[(size_t)b * DMODEL + d] = yv;
        }
    }
}

// ---------------------------------------------------------------------------
// LayerNorm(last token) + head. One block per batch.
// ---------------------------------------------------------------------------
__global__ __launch_bounds__(256) void ln_head_kernel(
    const float* __restrict__ ylast, const float* __restrict__ g,
    const float* __restrict__ bb, const float* __restrict__ hw,
    const float* __restrict__ hb, float* __restrict__ out)
{
    const int b = blockIdx.x;
    const int tid = threadIdx.x;
    const float* row = ylast + (size_t)b * DMODEL;
    float v0 = row[tid], v1 = row[tid + 256];
    float s = v0 + v1;
    float s2 = v0 * v0 + v1 * v1;
#pragma unroll
    for (int o = 32; o >= 1; o >>= 1) {
        s += __shfl_xor(s, o);
        s2 += __shfl_xor(s2, o);
    }
    __shared__ float red[8];
    const int w = tid >> 6;
    if ((tid & 63) == 0) { red[w] = s; red[4 + w] = s2; }
    __syncthreads();
    s = red[0] + red[1] + red[2] + red[3];
    s2 = red[4] + red[5] + red[6] + red[7];
    float mu = s * (1.f / DMODEL);
    float var = s2 * (1.f / DMODEL) - mu * mu;
    float r = rsqrtf(var + LN_EPS);
    float c = ((v0 - mu) * r * g[tid] + bb[tid]) * hw[tid]
            + ((v1 - mu) * r * g[tid + 256] + bb[tid + 256]) * hw[tid + 256];
#pragma unroll
    for (int o = 32; o >= 1; o >>= 1) c += __shfl_xor(c, o);
    __syncthreads();
    if ((tid & 63) == 0) red[w] = c;
    __syncthreads();
    if (tid == 0) out[b] = red[0] + red[1] + red[2] + red[3] + hb[0];
}

// ---------------------------------------------------------------------------
extern "C" void kernel_launch(void* const* d_in, const int* in_sizes, int n_in,
                              void* d_out, int out_size, void* d_ws, size_t ws_size,
                              hipStream_t stream)
{
    const float* x      = (const float*)d_in[0];
    const float* W_in0  = (const float*)d_in[1];
    const float* b_in0  = (const float*)d_in[2];
    const float* W_in   = (const float*)d_in[3];
    const float* b_in   = (const float*)d_in[4];
    const float* A_log  = (const float*)d_in[5];
    const float* D_skip = (const float*)d_in[6];
    const float* W_dt   = (const float*)d_in[7];
    const float* b_dt   = (const float*)d_in[8];
    const float* W_B    = (const float*)d_in[9];
    const float* W_C    = (const float*)d_in[10];
    const float* ln_g   = (const float*)d_in[11];
    const float* ln_b   = (const float*)d_in[12];
    const float* head_w = (const float*)d_in[13];
    const float* head_b = (const float*)d_in[14];
    float* out = (float*)d_out;

    const size_t BLD = (size_t)B_SZ * L_SZ * DMODEL;         // 16.78M
    const size_t BLN = (size_t)B_SZ * L_SZ * DSTATE;         // 0.52M
    const size_t BCD = (size_t)B_SZ * NC * DMODEL * DSTATE;  // 4.19M
    const size_t XBN = (size_t)B_SZ * L_SZ * DIN;            // 2.10M

    float* fp = (float*)d_ws;
    float* Bbuf  = fp; fp += BLN;
    float* Cbuf  = fp; fp += BLN;
    float* Pbuf  = fp; fp += BCD;
    float* Sbuf  = fp; fp += BCD;
    float* H0buf = fp; fp += BCD;
    float* ylast = fp; fp += (size_t)B_SZ * DMODEL;
    float* biascat = fp; fp += (size_t)NLAYERS * NFUSED;
    u16* hp = (u16*)fp;
    u16* xb    = hp; hp += XBN;
    u16* ub    = hp; hp += BLD;
    u16* dtb   = hp; hp += BLD;
    u16* ybuf  = hp; hp += BLD;
    u16* BT0   = hp; hp += (size_t)NFUSED * DIN;                    // layer 0
    u16* BTcat = hp; hp += (size_t)(NLAYERS - 1) * NFUSED * DMODEL; // layers 1-3
    u16* WBCT  = hp; hp += (size_t)NLAYERS * 32 * DMODEL;

    const int M = B_SZ * L_SZ;   // 32768

    // ---- prep ----
    castx<<<(XBN / 4 + 255) / 256, 256, 0, stream>>>(x, xb, XBN / 4);
    prep_wbc<<<(NLAYERS * 32 * DMODEL) / 256, 256, 0, stream>>>(W_B, W_C, WBCT);
    // layer 0: BT0 = [W_in0^T | (W_in0@W_dt0)^T]  (1024 rows, K=64)
    wtrans<<<dim3(DIN / 32, DMODEL / 32, 1), 256, 0, stream>>>(
        W_in0, BT0, DIN, DMODEL, 0, 0);
    wcombo<<<dim3(DIN / 16, DMODEL / 16, 1), 256, 0, stream>>>(
        W_in0, W_dt, BT0 + (size_t)DMODEL * DIN, DIN, 0, 0, 0);
    biasprep<<<dim3(4, 1, 1), 256, 0, stream>>>(
        b_in0, W_dt, b_dt, biascat, 0, 0, 0, 0);
    // layers 1-3 batched over z
    wtrans<<<dim3(DMODEL / 32, DMODEL / 32, NLAYERS - 1), 256, 0, stream>>>(
        W_in, BTcat, DMODEL, DMODEL,
        (size_t)DMODEL * DMODEL, (size_t)NFUSED * DMODEL);
    wcombo<<<dim3(DMODEL / 16, DMODEL / 16, NLAYERS - 1), 256, 0, stream>>>(
        W_in, W_dt + (size_t)DMODEL * DMODEL,
        BTcat + (size_t)DMODEL * DMODEL, DMODEL,
        (size_t)DMODEL * DMODEL, (size_t)DMODEL * DMODEL,
        (size_t)NFUSED * DMODEL);
    biasprep<<<dim3(4, 1, NLAYERS - 1), 256, 0, stream>>>(
        b_in, W_dt + (size_t)DMODEL * DMODEL, b_dt + DMODEL, biascat + NFUSED,
        DMODEL, (size_t)DMODEL * DMODEL, DMODEL, NFUSED);

    // ---- layers ----
    for (int l = 0; l < NLAYERS; ++l) {
        if (l == 0) {
            gemm_fused<DIN><<<(M / 128) * (NFUSED / 128), 512, 0, stream>>>(
                xb, BT0, biascat, ub, dtb, M);
        } else {
            gemm_fused<DMODEL><<<(M / 128) * (NFUSED / 128), 512, 0, stream>>>(
                ybuf, BTcat + (size_t)(l - 1) * NFUSED * DMODEL,
                biascat + (size_t)l * NFUSED, ub, dtb, M);
        }
        gemm_bc_mfma<<<M / 64, 256, 0, stream>>>(
            ub, WBCT + (size_t)l * 32 * DMODEL, Bbuf, Cbuf);
        const float* Al = A_log + (size_t)l * DMODEL * DSTATE;
        scan_pass1<<<dim3(DMODEL / 256, NC, B_SZ), 256, 0, stream>>>(
            ub, dtb, Bbuf, Al, Pbuf, Sbuf);
        scan_fix<<<(B_SZ * DMODEL * DSTATE) / 256, 256, 0, stream>>>(
            Pbuf, Sbuf, H0buf);
        scan_pass2<<<dim3(DMODEL / 256, NC, B_SZ), 256, 0, stream>>>(
            ub, dtb, Bbuf, Cbuf, Al, D_skip + (size_t)l * DMODEL,
            H0buf, ybuf, ylast);
    }

    ln_head_kernel<<<B_SZ, 256, 0, stream>>>(ylast, ln_g, ln_b, head_w, head_b, out);
}